// Round 7
// baseline (58.447 us; speedup 1.0000x reference)
//
#include <hip/hip_runtime.h>
#include <hip/hip_bf16.h>

#define NN 4096
#define DD 512
#define TILE 64
#define NCH (NN / TILE)                 // 64 tile-chunks per side
#define NTRI (NCH * (NCH + 1) / 2)      // 2080 upper-triangle blocks
#define NSTEP (DD / 32)                 // 16 K-steps

typedef unsigned short u16;
typedef __attribute__((ext_vector_type(4))) float f32x4;
typedef __attribute__((ext_vector_type(8))) short bf16x8;

// ws layout (bytes):
#define OFF_DVAL ((size_t)NN * DD * 2)                 // xbf: NN*DD u16
#define OFF_DINC (OFF_DVAL + (size_t)NN * 4)           // exact diag f32
#define OFF_HIST (OFF_DINC + (size_t)NN * 4)           // include flag f32
#define OFF_LRP  (OFF_HIST + 256 * 4)                  // class histogram i32
#define OFF_PART (OFF_LRP + (size_t)NCH * 2 * 4)       // last-row partials
#define OFF_BS   (OFF_PART + (size_t)NCH * NN * 2 * 4) // per-chunk {pl,nl} 2MB
// OFF_BS: 16 blocks x {loss,inv} f64; total ~6.3 MB

__device__ __forceinline__ float softplus_fast(float z) {
  return __logf(1.0f + __expf(z));
}

__device__ __forceinline__ void gload_lds16(const u16* g, void* l) {
  __builtin_amdgcn_global_load_lds(
      (const __attribute__((address_space(1))) void*)g,
      (__attribute__((address_space(3))) void*)l, 16, 0, 0);
}

// ---------------------------------------------------------------------------
// prep (2 roles): rows -> bf16 + exact f64 sumsq (diag decision); histogram.
__global__ __launch_bounds__(256) void prep_kernel(
    const float* __restrict__ x, const int* __restrict__ tg,
    u16* __restrict__ xbf, float* __restrict__ dval, float* __restrict__ dinc,
    int* __restrict__ hist) {
  const int bid = blockIdx.x;
  const int t = threadIdx.x;
  if (bid < NN / 4) {
    const int wid = t >> 6, lane = t & 63;
    const int row = bid * 4 + wid;
    const float* xr = x + (size_t)row * DD;
    u16* xb = xbf + (size_t)row * DD;
    double s = 0.0;
#pragma unroll
    for (int c = 0; c < DD / 64; ++c) {
      float v = xr[c * 64 + lane];
      s += (double)v * (double)v;
      __hip_bfloat16 b = __float2bfloat16(v);
      xb[c * 64 + lane] = *reinterpret_cast<const u16*>(&b);
    }
#pragma unroll
    for (int m = 32; m; m >>= 1) s += __shfl_xor(s, m, 64);
    if (lane == 0) {
      float sf = (float)s;
      dval[row] = sf;
      dinc[row] = (sf < 1.0f) ? 1.0f : 0.0f;  // ref: pos includes diag iff sim<1
    }
  } else {
    __shared__ int h[256];
    h[t] = 0;
    __syncthreads();
    const int base = t * (NN / 256);
#pragma unroll
    for (int k = 0; k < NN / 256; ++k) atomicAdd(&h[tg[base + k]], 1);
    __syncthreads();
    hist[t] = h[t];
  }
}

// ---------------------------------------------------------------------------
// main: ONE WAVE per block, 64x64 tile, upper triangle (2080 blocks).
// No barriers at all: the wave stages its own LDS double-buffer with
// global_load_lds and synchronizes with counted `s_waitcnt vmcnt(8)` so the
// next step's 8 staging loads stay in flight under this step's ds_read+MFMA.
// Epilogue: exp()-only negatives, rare-branch positives, 4-shuffle row
// reduce, direct float2 stores of row/col partial sums (symmetry for cols).
__global__ __launch_bounds__(64, 4) void sim_kernel(
    const u16* __restrict__ xbf, const int* __restrict__ tg,
    float* __restrict__ part, float* __restrict__ lrp) {
  __shared__ __align__(16) u16 sA[2][TILE * 32];   // [buf][64 rows][32 k]
  __shared__ __align__(16) u16 sB[2][TILE * 32];

  // triangular decode: bi <= bj
  int l = blockIdx.x, bi = 0, span = NCH;
  while (l >= span) { l -= span; ++bi; --span; }
  const int bj = bi + l;
  const bool offdiag = (bi != bj);

  const int t = threadIdx.x;              // == lane (1 wave)
  const int q = t >> 4, lr = t & 15;
  const int rowBase = bi * TILE, colBase = bj * TILE;

  // staging source: lane covers row (g*16 + t>>2), k-bytes (t&3)*16
  const u16* gA0 = xbf + (size_t)(rowBase + (t >> 2)) * DD + (t & 3) * 8;
  const u16* gB0 = xbf + (size_t)(colBase + (t >> 2)) * DD + (t & 3) * 8;

#define STAGE(S, B)                                                      \
  do {                                                                   \
    _Pragma("unroll")                                                    \
    for (int g = 0; g < 4; ++g) {                                        \
      gload_lds16(gA0 + (size_t)g * 16 * DD + (S) * 32,                  \
                  (char*)&sA[(B)][0] + g * 1024);                        \
      gload_lds16(gB0 + (size_t)g * 16 * DD + (S) * 32,                  \
                  (char*)&sB[(B)][0] + g * 1024);                        \
    }                                                                    \
  } while (0)

  f32x4 acc[4][4] = {};

#define KSTEP(S, CUR, WN, DOSTAGE)                                       \
  do {                                                                   \
    asm volatile("s_waitcnt vmcnt(" #WN ")" ::: "memory");               \
    bf16x8 af[4], bg[4];                                                 \
    _Pragma("unroll")                                                    \
    for (int m = 0; m < 4; ++m) {                                        \
      af[m] = *reinterpret_cast<const bf16x8*>(                          \
          &sA[CUR][(m * 16 + lr) * 32 + q * 8]);                         \
      bg[m] = *reinterpret_cast<const bf16x8*>(                          \
          &sB[CUR][(m * 16 + lr) * 32 + q * 8]);                         \
    }                                                                    \
    _Pragma("unroll")                                                    \
    for (int m = 0; m < 4; ++m)                                          \
      _Pragma("unroll")                                                  \
      for (int n = 0; n < 4; ++n)                                        \
        acc[m][n] = __builtin_amdgcn_mfma_f32_16x16x32_bf16(             \
            af[m], bg[n], acc[m][n], 0, 0, 0);                           \
    if (DOSTAGE) STAGE((S) + 2, CUR);                                    \
  } while (0)

  STAGE(0, 0);                     // 8 loads in flight
  STAGE(1, 1);                     // 16 in flight
#pragma unroll 1
  for (int s = 0; s < NSTEP - 2; s += 2) {
    KSTEP(s, 0, 8, true);          // wait STAGE(s); prefetch STAGE(s+2)
    KSTEP(s + 1, 1, 8, true);
  }
  KSTEP(NSTEP - 2, 0, 8, false);
  KSTEP(NSTEP - 1, 1, 0, false);
#undef KSTEP
#undef STAGE

  // ---- epilogue. C/D layout: col=lane&15, row=(lane>>4)*4+j (m89-verified).
  int tc[4];
#pragma unroll
  for (int n = 0; n < 4; ++n) tc[n] = tg[colBase + n * 16 + lr];

  float colP[4] = {0.f, 0.f, 0.f, 0.f}, colN[4] = {0.f, 0.f, 0.f, 0.f};

#pragma unroll
  for (int m = 0; m < 4; ++m) {
#pragma unroll
    for (int j = 0; j < 4; ++j) {
      const int ri = rowBase + m * 16 + q * 4 + j;
      const int trr = tg[ri];
      float pl = 0.f, nl = 0.f;
#pragma unroll
      for (int n = 0; n < 4; ++n) {
        const float sim = acc[m][n][j];
        const float z = __fmaf_rn(40.0f, sim, -20.0f);
        float e = __expf(z);                  // == softplus(z) for z <= -8
        if (z > -8.0f) e = __logf(1.0f + e);  // exactness guard (cold)
        const bool same = (trr == tc[n]);
        const float nv = same ? 0.0f : e;
        nl += nv;
        colN[n] += nv;
        if (same) {                           // rare exec-masked branch
          const int cj = colBase + n * 16 + lr;
          if (ri != cj) {                     // diag handled analytically
            const float sp = softplus_fast(__fmaf_rn(-2.0f, sim, 1.0f));
            pl += sp;
            colP[n] += sp;
          }
        }
      }
      // reduce over the 16 lanes (cols) sharing this row
#pragma unroll
      for (int s = 8; s; s >>= 1) {
        pl += __shfl_xor(pl, s, 64);
        nl += __shfl_xor(nl, s, 64);
      }
      if (lr == 0) {
        float2 v = {pl, nl};
        *reinterpret_cast<float2*>(&part[((size_t)bj * NN + ri) * 2]) = v;
      }
    }
  }

  // column sums -> tile bj rows, chunk bi (symmetry); offdiag only
  if (offdiag) {
#pragma unroll
    for (int n = 0; n < 4; ++n) {
      colP[n] += __shfl_xor(colP[n], 16, 64);
      colP[n] += __shfl_xor(colP[n], 32, 64);
      colN[n] += __shfl_xor(colN[n], 16, 64);
      colN[n] += __shfl_xor(colN[n], 32, 64);
    }
    if (q == 0) {
#pragma unroll
      for (int n = 0; n < 4; ++n) {
        float2 v = {colP[n], colN[n]};
        *reinterpret_cast<float2*>(
            &part[((size_t)bi * NN + colBase + n * 16 + lr) * 2]) = v;
      }
    }
  }

  // last-row (4095) sim partials: blocks with bj == NCH-1 (col 4095 = n3,lr15)
  if (bj == NCH - 1) {
    const int tgl = tc[3];
    const bool isc = (lr == 15);
    float ssl = 0.f, nsl = 0.f;
#pragma unroll
    for (int m = 0; m < 4; ++m)
#pragma unroll
      for (int j = 0; j < 4; ++j) {
        const int ri = rowBase + m * 16 + q * 4 + j;
        const float sim = acc[m][3][j];
        const bool same = (tg[ri] == tgl);
        ssl += (isc && same && ri != NN - 1) ? sim : 0.f;
        nsl += (isc && !same) ? sim : 0.f;
      }
#pragma unroll
    for (int mm = 32; mm; mm >>= 1) {
      ssl += __shfl_xor(ssl, mm, 64);
      nsl += __shfl_xor(nsl, mm, 64);
    }
    if (t == 0) { lrp[bi * 2 + 0] = ssl; lrp[bi * 2 + 1] = nsl; }
  }
}

// ---------------------------------------------------------------------------
// finalize 1: per-row combine over 64 chunks + analytic diagonal + histogram
// counts; block-level f64 tree reduce -> 16 partials. Row 4095 emits
// last_pos/last_neg from the sim-block partials.
__global__ __launch_bounds__(256) void fin1_kernel(
    const float* __restrict__ part, const float* __restrict__ dval,
    const float* __restrict__ dinc, const int* __restrict__ hist,
    const int* __restrict__ tg, const float* __restrict__ lrp,
    double* __restrict__ bsums, float* __restrict__ out) {
  const int t = threadIdx.x;
  const int r = blockIdx.x * 256 + t;
  float pl = 0.f, nl = 0.f;
  for (int c = 0; c < NCH; ++c) {
    const float* p = part + ((size_t)c * NN + r) * 2;
    pl += p[0]; nl += p[1];
  }
  const float inc = dinc[r], dv = dval[r];
  const float scnt = (float)(hist[tg[r]] - 1);   // off-diag same-class count
  const float pos_cnt = scnt + inc;
  const float pos_sum = pl + inc * softplus_fast(__fmaf_rn(-2.0f, dv, 1.0f));
  const float pos_loss = pos_sum / fmaxf(pos_cnt, 1.0f);
  const float neg_cnt = 4095.0f - scnt;
  const float neg_loss = nl / fmaxf(neg_cnt, 1.0f);
  const bool valid = neg_cnt > 0.0f;

  __shared__ double sl[256];
  __shared__ double si[256];
  sl[t] = valid ? (double)(pos_loss + neg_loss) : 0.0;
  si[t] = valid ? 0.0 : 1.0;
  __syncthreads();
  for (int s = 128; s; s >>= 1) {
    if (t < s) { sl[t] += sl[t + s]; si[t] += si[t + s]; }
    __syncthreads();
  }
  if (t == 0) { bsums[blockIdx.x * 2] = sl[0]; bsums[blockIdx.x * 2 + 1] = si[0]; }

  if (r == NN - 1) {
    float ss = 0.f, ns = 0.f;
    for (int c = 0; c < NCH; ++c) { ss += lrp[c * 2]; ns += lrp[c * 2 + 1]; }
    out[2] = (ss + inc * dv) / fmaxf(pos_cnt, 1.0f);
    out[3] = ns / fmaxf(neg_cnt, 1.0f);
  }
}

// finalize 2: tiny — sum 16 block partials.
__global__ __launch_bounds__(64) void fin2_kernel(
    const double* __restrict__ bsums, float* __restrict__ out) {
  if (threadIdx.x == 0) {
    double l = 0.0, iv = 0.0;
    for (int b = 0; b < NN / 256; ++b) { l += bsums[b * 2]; iv += bsums[b * 2 + 1]; }
    out[0] = (float)(l / NN);
    out[1] = (float)(iv / NN);
  }
}

extern "C" void kernel_launch(void* const* d_in, const int* in_sizes, int n_in,
                              void* d_out, int out_size, void* d_ws, size_t ws_size,
                              hipStream_t stream) {
  const float* x = (const float*)d_in[0];
  const int* tg = (const int*)d_in[1];
  float* out = (float*)d_out;
  char* ws = (char*)d_ws;

  u16*    xbf  = (u16*)ws;
  float*  dval = (float*)(ws + OFF_DVAL);
  float*  dinc = (float*)(ws + OFF_DINC);
  int*    hist = (int*)(ws + OFF_HIST);
  float*  lrp  = (float*)(ws + OFF_LRP);
  float*  part = (float*)(ws + OFF_PART);
  double* bs   = (double*)(ws + OFF_BS);

  prep_kernel<<<NN / 4 + 1, 256, 0, stream>>>(x, tg, xbf, dval, dinc, hist);
  sim_kernel<<<NTRI, 64, 0, stream>>>(xbf, tg, part, lrp);
  fin1_kernel<<<NN / 256, 256, 0, stream>>>(part, dval, dinc, hist, tg, lrp, bs, out);
  fin2_kernel<<<1, 64, 0, stream>>>(bs, out);
}

// Round 8
// 48.120 us; speedup vs baseline: 1.2146x; 1.2146x over previous
//
#include <hip/hip_runtime.h>
#include <hip/hip_bf16.h>

#define NN 4096
#define DD 512
#define TILE 128
#define NCH (NN / TILE)                 // 32 tile-chunks per side
#define NSTEP (DD / 32)                 // 16 K-steps

typedef unsigned short u16;
typedef __attribute__((ext_vector_type(4))) float f32x4;
typedef __attribute__((ext_vector_type(8))) short bf16x8;

// ws layout (bytes):
#define OFF_DVAL ((size_t)NN * DD * 2)                 // xbf: NN*DD u16
#define OFF_DINC (OFF_DVAL + (size_t)NN * 4)           // exact diag f32
#define OFF_HIST (OFF_DINC + (size_t)NN * 4)           // include flag f32
#define OFF_LRP  (OFF_HIST + 256 * 4)                  // class histogram i32
#define OFF_PART (OFF_LRP + (size_t)NCH * 2 * 4)       // last-row partials
#define OFF_BS   (OFF_PART + (size_t)NCH * NN * 2 * 4) // per-chunk {pl,nl} 1MB
// OFF_BS: 16 blocks x {loss,inv} f64

__device__ __forceinline__ float softplus_fast(float z) {
  return __logf(1.0f + __expf(z));
}

__device__ __forceinline__ void gload_lds16(const u16* g, void* l) {
  __builtin_amdgcn_global_load_lds(
      (const __attribute__((address_space(1))) void*)g,
      (__attribute__((address_space(3))) void*)l, 16, 0, 0);
}

// ---------------------------------------------------------------------------
// prep (2 roles): rows -> bf16 + exact f64 sumsq (diag decision); histogram.
__global__ __launch_bounds__(256) void prep_kernel(
    const float* __restrict__ x, const int* __restrict__ tg,
    u16* __restrict__ xbf, float* __restrict__ dval, float* __restrict__ dinc,
    int* __restrict__ hist) {
  const int bid = blockIdx.x;
  const int t = threadIdx.x;
  if (bid < NN / 4) {
    const int wid = t >> 6, lane = t & 63;
    const int row = bid * 4 + wid;
    const float* xr = x + (size_t)row * DD;
    u16* xb = xbf + (size_t)row * DD;
    double s = 0.0;
#pragma unroll
    for (int c = 0; c < DD / 64; ++c) {
      float v = xr[c * 64 + lane];
      s += (double)v * (double)v;
      __hip_bfloat16 b = __float2bfloat16(v);
      xb[c * 64 + lane] = *reinterpret_cast<const u16*>(&b);
    }
#pragma unroll
    for (int m = 32; m; m >>= 1) s += __shfl_xor(s, m, 64);
    if (lane == 0) {
      float sf = (float)s;
      dval[row] = sf;
      dinc[row] = (sf < 1.0f) ? 1.0f : 0.0f;  // ref: pos includes diag iff sim<1
    }
  } else {
    __shared__ int h[256];
    h[t] = 0;
    __syncthreads();
    const int base = t * (NN / 256);
#pragma unroll
    for (int k = 0; k < NN / 256; ++k) atomicAdd(&h[tg[base + k]], 1);
    __syncthreads();
    hist[t] = h[t];
  }
}

// ---------------------------------------------------------------------------
// main: FULL 32x32 grid of 128x128 tiles (1024 blocks -> 4/CU co-resident;
// TLP hides the per-step barrier drain). 4 waves, dbuf LDS, 1 barrier/step.
// Cheap epilogue: exp-only negatives (softplus(z)==e^z for z<=-8, guarded),
// rare exec-masked positives, LDS-transpose row reduce (stride-133 pad).
// bj==NCH-1 blocks extract last-row (4095) {pos_sim,neg_sim} from acc.
__global__ __launch_bounds__(256, 4) void sim_kernel(
    const u16* __restrict__ xbf, const int* __restrict__ tg,
    float* __restrict__ part, float* __restrict__ lrp) {
  // union: K-loop staging (32768 B) / epilogue red2 [2][32][133] f32 (34048 B)
  __shared__ __align__(16) char smem[34048];
  __shared__ float lrr[2][2];          // last-row partials, [wR][var]

  const int bx = blockIdx.x;
  const int bi = bx >> 5, bj = bx & 31;

  const int t = threadIdx.x;
  const int lane = t & 63, wid = t >> 6;
  const int wR = wid >> 1, wC = wid & 1;          // 2x2 wave grid, 64x64 each
  const int q = lane >> 4, lr = lane & 15;
  const int rowBase = bi * TILE, colBase = bj * TILE;

  const int r0 = t >> 2;            // 0..63
  const int kk = (t & 3) * 8;       // 0,8,16,24
  const u16* gA0 = xbf + (size_t)(rowBase + r0) * DD + kk;
  const u16* gB0 = xbf + (size_t)(colBase + r0) * DD + kk;
  u16* sA = (u16*)smem;             // sA[buf][4096], sB[buf][4096] u16
  u16* sB = (u16*)smem + 8192;

#define STAGE(kb, b)                                            \
  do {                                                          \
    char* lA_ = (char*)(sA + (b) * 4096) + wid * 1024;          \
    char* lB_ = (char*)(sB + (b) * 4096) + wid * 1024;          \
    gload_lds16(gA0 + (kb), lA_);                               \
    gload_lds16(gA0 + (kb) + 64 * DD, lA_ + 4096);              \
    gload_lds16(gB0 + (kb), lB_);                               \
    gload_lds16(gB0 + (kb) + 64 * DD, lB_ + 4096);              \
  } while (0)

  f32x4 acc[4][4] = {};

  STAGE(0, 0);
  __syncthreads();

#pragma unroll 2
  for (int s = 0; s < NSTEP; ++s) {
    const int cur = s & 1;
    if (s + 1 < NSTEP) STAGE((s + 1) * 32, cur ^ 1);

    bf16x8 af[4], bg[4];
#pragma unroll
    for (int m = 0; m < 4; ++m) {
      af[m] = *reinterpret_cast<const bf16x8*>(&sA[cur * 4096 + (wR * 64 + m * 16 + lr) * 32 + q * 8]);
      bg[m] = *reinterpret_cast<const bf16x8*>(&sB[cur * 4096 + (wC * 64 + m * 16 + lr) * 32 + q * 8]);
    }
#pragma unroll
    for (int m = 0; m < 4; ++m)
#pragma unroll
      for (int n = 0; n < 4; ++n)
        acc[m][n] = __builtin_amdgcn_mfma_f32_16x16x32_bf16(af[m], bg[n], acc[m][n], 0, 0, 0);
    __syncthreads();   // also guards smem reuse by epilogue
  }
#undef STAGE

  // ---- epilogue. C/D layout: col=lane&15, row=(lane>>4)*4+j (m89-verified).
  int tc[4];
#pragma unroll
  for (int n = 0; n < 4; ++n) tc[n] = tg[colBase + wC * 64 + n * 16 + lr];

  float plv[4][4], nlv[4][4];
#pragma unroll
  for (int m = 0; m < 4; ++m)
#pragma unroll
    for (int j = 0; j < 4; ++j) { plv[m][j] = 0.f; nlv[m][j] = 0.f; }

#pragma unroll
  for (int m = 0; m < 4; ++m) {
#pragma unroll
    for (int j = 0; j < 4; ++j) {
      const int ri = rowBase + wR * 64 + m * 16 + q * 4 + j;
      const int trr = tg[ri];
#pragma unroll
      for (int n = 0; n < 4; ++n) {
        const float sim = acc[m][n][j];
        const float z = __fmaf_rn(40.0f, sim, -20.0f);
        float e = __expf(z);                  // == softplus(z) for z <= -8
        if (z > -8.0f) e = __logf(1.0f + e);  // exactness guard (cold)
        const bool same = (trr == tc[n]);
        nlv[m][j] += same ? 0.0f : e;
        if (same) {                           // rare exec-masked branch
          const int cj = colBase + wC * 64 + n * 16 + lr;
          if (ri != cj) {                     // diag handled analytically
            plv[m][j] += softplus_fast(__fmaf_rn(-2.0f, sim, 1.0f));
          }
        }
      }
    }
  }

  // last-row (4095) sim partials BEFORE smem reuse: bj == NCH-1 blocks.
  if (bj == NCH - 1) {
    const int tgl = tc[3];  // meaningful where lr==15 (col 4095)
    float ssl = 0.f, nsl = 0.f;
    const bool isc = (wC == 1) && (lr == 15);
#pragma unroll
    for (int m = 0; m < 4; ++m)
#pragma unroll
      for (int j = 0; j < 4; ++j) {
        const int ri = rowBase + wR * 64 + m * 16 + q * 4 + j;
        const float sim = acc[m][3][j];
        const bool same = (tg[ri] == tgl);
        ssl += (isc && same && ri != NN - 1) ? sim : 0.f;
        nsl += (isc && !same) ? sim : 0.f;
      }
#pragma unroll
    for (int mm = 32; mm; mm >>= 1) {
      ssl += __shfl_xor(ssl, mm, 64);
      nsl += __shfl_xor(nsl, mm, 64);
    }
    if (wC == 1 && lane == 0) { lrr[wR][0] = ssl; lrr[wR][1] = nsl; }
  }

  // row-partial transpose into LDS: red2[var][slot 32][133] f32
  float* red2f = (float*)smem;
  const int slot = wC * 16 + lr;
#pragma unroll
  for (int m = 0; m < 4; ++m) {
    const int row0 = wR * 64 + m * 16 + q * 4;
    f32x4 pv = {plv[m][0], plv[m][1], plv[m][2], plv[m][3]};
    f32x4 nv = {nlv[m][0], nlv[m][1], nlv[m][2], nlv[m][3]};
    *reinterpret_cast<f32x4*>(&red2f[(0 * 32 + slot) * 133 + row0]) = pv;
    *reinterpret_cast<f32x4*>(&red2f[(1 * 32 + slot) * 133 + row0]) = nv;
  }
  __syncthreads();

  // final reduce: thread (var,row) sums 32 slots, writes part directly.
  {
    const int var = t >> 7, row = t & 127;
    float s0 = 0.f, s1 = 0.f, s2 = 0.f, s3 = 0.f;
#pragma unroll
    for (int sl = 0; sl < 32; sl += 4) {
      s0 += red2f[(var * 32 + sl + 0) * 133 + row];
      s1 += red2f[(var * 32 + sl + 1) * 133 + row];
      s2 += red2f[(var * 32 + sl + 2) * 133 + row];
      s3 += red2f[(var * 32 + sl + 3) * 133 + row];
    }
    part[((size_t)bj * NN + (rowBase + row)) * 2 + var] = (s0 + s1) + (s2 + s3);
  }
  if (bj == NCH - 1 && t == 0) {
    lrp[bi * 2 + 0] = lrr[0][0] + lrr[1][0];
    lrp[bi * 2 + 1] = lrr[0][1] + lrr[1][1];
  }
}

// ---------------------------------------------------------------------------
// finalize 1: per-row combine over 32 chunks + analytic diagonal + histogram
// counts; block-level f64 tree reduce -> 16 partials. Row 4095 emits
// last_pos/last_neg from the sim-block partials.
__global__ __launch_bounds__(256) void fin1_kernel(
    const float* __restrict__ part, const float* __restrict__ dval,
    const float* __restrict__ dinc, const int* __restrict__ hist,
    const int* __restrict__ tg, const float* __restrict__ lrp,
    double* __restrict__ bsums, float* __restrict__ out) {
  const int t = threadIdx.x;
  const int r = blockIdx.x * 256 + t;
  float pl = 0.f, nl = 0.f;
  for (int c = 0; c < NCH; ++c) {
    const float* p = part + ((size_t)c * NN + r) * 2;
    pl += p[0]; nl += p[1];
  }
  const float inc = dinc[r], dv = dval[r];
  const float scnt = (float)(hist[tg[r]] - 1);   // off-diag same-class count
  const float pos_cnt = scnt + inc;
  const float pos_sum = pl + inc * softplus_fast(__fmaf_rn(-2.0f, dv, 1.0f));
  const float pos_loss = pos_sum / fmaxf(pos_cnt, 1.0f);
  const float neg_cnt = 4095.0f - scnt;
  const float neg_loss = nl / fmaxf(neg_cnt, 1.0f);
  const bool valid = neg_cnt > 0.0f;

  __shared__ double sl[256];
  __shared__ double si[256];
  sl[t] = valid ? (double)(pos_loss + neg_loss) : 0.0;
  si[t] = valid ? 0.0 : 1.0;
  __syncthreads();
  for (int s = 128; s; s >>= 1) {
    if (t < s) { sl[t] += sl[t + s]; si[t] += si[t + s]; }
    __syncthreads();
  }
  if (t == 0) { bsums[blockIdx.x * 2] = sl[0]; bsums[blockIdx.x * 2 + 1] = si[0]; }

  if (r == NN - 1) {
    float ss = 0.f, ns = 0.f;
    for (int c = 0; c < NCH; ++c) { ss += lrp[c * 2]; ns += lrp[c * 2 + 1]; }
    out[2] = (ss + inc * dv) / fmaxf(pos_cnt, 1.0f);
    out[3] = ns / fmaxf(neg_cnt, 1.0f);
  }
}

// finalize 2: tiny — sum 16 block partials.
__global__ __launch_bounds__(64) void fin2_kernel(
    const double* __restrict__ bsums, float* __restrict__ out) {
  if (threadIdx.x == 0) {
    double l = 0.0, iv = 0.0;
    for (int b = 0; b < NN / 256; ++b) { l += bsums[b * 2]; iv += bsums[b * 2 + 1]; }
    out[0] = (float)(l / NN);
    out[1] = (float)(iv / NN);
  }
}

extern "C" void kernel_launch(void* const* d_in, const int* in_sizes, int n_in,
                              void* d_out, int out_size, void* d_ws, size_t ws_size,
                              hipStream_t stream) {
  const float* x = (const float*)d_in[0];
  const int* tg = (const int*)d_in[1];
  float* out = (float*)d_out;
  char* ws = (char*)d_ws;

  u16*    xbf  = (u16*)ws;
  float*  dval = (float*)(ws + OFF_DVAL);
  float*  dinc = (float*)(ws + OFF_DINC);
  int*    hist = (int*)(ws + OFF_HIST);
  float*  lrp  = (float*)(ws + OFF_LRP);
  float*  part = (float*)(ws + OFF_PART);
  double* bs   = (double*)(ws + OFF_BS);

  prep_kernel<<<NN / 4 + 1, 256, 0, stream>>>(x, tg, xbf, dval, dinc, hist);
  sim_kernel<<<NCH * NCH, 256, 0, stream>>>(xbf, tg, part, lrp);
  fin1_kernel<<<NN / 256, 256, 0, stream>>>(part, dval, dinc, hist, tg, lrp, bs, out);
  fin2_kernel<<<1, 64, 0, stream>>>(bs, out);
}